// Round 1
// baseline (324.974 us; speedup 1.0000x reference)
//
#include <hip/hip_runtime.h>

typedef __attribute__((ext_vector_type(8))) short short8;
typedef __attribute__((ext_vector_type(4))) short short4v;
typedef __attribute__((ext_vector_type(4))) float floatx4;

#define MFMA16(a, b, c) __builtin_amdgcn_mfma_f32_16x16x32_bf16((a), (b), (c), 0, 0, 0)

#define LD32 36   // LDS row stride (elems) for 32-wide tiles: 8B-aligned frags, <=2-way banks
#define LD64 68   // LDS row stride (elems) for 64-wide tiles

__device__ __forceinline__ float bf2f(unsigned short u) {
  return __uint_as_float(((unsigned int)u) << 16);
}
__device__ __forceinline__ unsigned short f2bf(float f) {
  unsigned int x = __float_as_uint(f);
  x += 0x7FFFu + ((x >> 16) & 1u);   // RNE; inputs here are finite
  return (unsigned short)(x >> 16);
}
__device__ __forceinline__ float ld_in(const void* p, long i, int isf32) {
  if (isf32) return ((const float*)p)[i];
  return bf2f(((const unsigned short*)p)[i]);
}
__device__ __forceinline__ short8 lds_ld8(const unsigned short* p) {
  short4v a = *(const short4v*)p;
  short4v b = *(const short4v*)(p + 4);
  return __builtin_shufflevector(a, b, 0, 1, 2, 3, 4, 5, 6, 7);
}
__device__ __forceinline__ void lds_st8(unsigned short* d, short8 v) {
  *(short4v*)d       = __builtin_shufflevector(v, v, 0, 1, 2, 3);
  *(short4v*)(d + 4) = __builtin_shufflevector(v, v, 4, 5, 6, 7);
}

// ---------------------------------------------------------------------------
// Kernel 0: detect whether inputs are fp32 or bf16.
// bf16 N(0,1) data: exponent <= ~129. fp32 data read as ushorts: even indices
// are float mantissa low bits -> exponent field ~uniform in [0,255]; over 2048
// even samples P(all < 141) ~ 0. flag=1 -> fp32, flag=0 -> bf16.
// ---------------------------------------------------------------------------
__global__ void detect_kernel(const unsigned short* __restrict__ in0, int* __restrict__ flag) {
  int t = threadIdx.x;  // 64 threads
  int bad = 0;
  for (int i = t; i < 4096; i += 64) {
    unsigned int e = (in0[i] >> 7) & 0xFFu;
    if (e >= 141u) bad = 1;  // |x| >= 2^14 or inf/nan -> not plausible bf16 data
  }
  unsigned long long m = __ballot(bad);
  if (t == 0) *flag = (m != 0ull) ? 1 : 0;
}

// ---------------------------------------------------------------------------
// Kernel 1: QKV projection. X[16384,256] @ W[256, 320] with relu + bias.
// col tile ct: 0 -> q/k cols 0..63, 1..4 -> v cols 0..255.
// Q,K row-major bf16 [B*4096, 32]; V stored TRANSPOSED: Vt[b][c][n], bf16.
// ---------------------------------------------------------------------------
__global__ __launch_bounds__(256)
void proj_kernel(const void* __restrict__ x,
                 const void* __restrict__ Wq, const void* __restrict__ bq,
                 const void* __restrict__ Wk, const void* __restrict__ bk,
                 const void* __restrict__ Wv, const void* __restrict__ bv,
                 unsigned short* __restrict__ Q, unsigned short* __restrict__ Kk,
                 unsigned short* __restrict__ Vt, const int* __restrict__ flag) {
  __shared__ unsigned short Al[64 * LD32];
  __shared__ unsigned short Bl[64 * LD32];
  const int isf32 = *flag;
  const int t = threadIdx.x;
  const int ct = (int)(blockIdx.x % 5u);
  const long row_base = (long)(blockIdx.x / 5u) * 64;
  const int wave = t >> 6, lane = t & 63, quad = lane >> 4, l15 = lane & 15;
  const int srow = t >> 2, sc8 = (t & 3) * 8;

  // weight source for the B-staging column this thread owns
  const int g_b = ct * 64 + srow;
  const void* Wsrc;
  int wstride, wcol;
  if (g_b < 32)      { Wsrc = Wq; wstride = 32;  wcol = g_b; }
  else if (g_b < 64) { Wsrc = Wk; wstride = 32;  wcol = g_b - 32; }
  else               { Wsrc = Wv; wstride = 256; wcol = g_b - 64; }

  floatx4 acc[4];
  acc[0] = acc[1] = acc[2] = acc[3] = (floatx4)0.0f;

  for (int ks = 0; ks < 8; ks++) {
    __syncthreads();
    {  // stage A tile 64x32 (convert to bf16)
      const long gi = (row_base + srow) * 256 + ks * 32 + sc8;
      short8 v;
      if (isf32) {
        const float* xf = (const float*)x;
#pragma unroll
        for (int j = 0; j < 8; j++) v[j] = (short)f2bf(xf[gi + j]);
      } else {
        v = *(const short8*)((const unsigned short*)x + gi);
      }
      lds_st8(&Al[srow * LD32 + sc8], v);
    }
    {  // stage B tile transposed: Bl[n][k] = W[ks*32+k][g]
      short8 v;
#pragma unroll
      for (int j = 0; j < 8; j++)
        v[j] = (short)f2bf(ld_in(Wsrc, (long)(ks * 32 + sc8 + j) * wstride + wcol, isf32));
      lds_st8(&Bl[srow * LD32 + sc8], v);
    }
    __syncthreads();
    const short8 a = lds_ld8(&Al[(wave * 16 + l15) * LD32 + quad * 8]);
#pragma unroll
    for (int tn = 0; tn < 4; tn++) {
      const short8 bfr = lds_ld8(&Bl[(tn * 16 + l15) * LD32 + quad * 8]);
      acc[tn] = MFMA16(a, bfr, acc[tn]);
    }
  }

#pragma unroll
  for (int tn = 0; tn < 4; tn++) {
    const int g = ct * 64 + tn * 16 + l15;
    float bias;
    if (g < 32) bias = ld_in(bq, g, isf32);
    else if (g < 64) bias = ld_in(bk, g - 32, isf32);
    else bias = ld_in(bv, g - 64, isf32);
#pragma unroll
    for (int r = 0; r < 4; r++) {
      const long row = row_base + wave * 16 + quad * 4 + r;  // = b*4096 + n
      const float vv = fmaxf(acc[tn][r] + bias, 0.0f);
      const unsigned short h = f2bf(vv);
      if (g < 32) Q[row * 32 + g] = h;
      else if (g < 64) Kk[row * 32 + (g - 32)] = h;
      else Vt[((row >> 12) * 256 + (long)(g - 64)) * 4096 + (row & 4095)] = h;
    }
  }
}

// ---------------------------------------------------------------------------
// Kernel 2: flash attention. Block = (batch, 64-row Q tile), 4 waves.
// Wave w owns output rows [16w,16w+16): softmax state never crosses waves.
// mfma_f32_16x16x32_bf16 layouts (verified m89/m91/m120):
//   A: lane holds A[m=lane&15][k=quad*8+j]; B: B[k=quad*8+j][n=lane&15]
//   C/D: col=lane&15, row=quad*4+reg
// ---------------------------------------------------------------------------
__global__ __launch_bounds__(256)
void flash_kernel(const unsigned short* __restrict__ Q,
                  const unsigned short* __restrict__ K,
                  const unsigned short* __restrict__ Vt,
                  unsigned short* __restrict__ O) {
  __shared__ unsigned short Ql[64 * LD32];
  __shared__ unsigned short Kl[64 * LD32];
  __shared__ unsigned short Vl[256 * LD64];  // Vl[n][k] = V[kt*64+k][n]
  __shared__ unsigned short Pl[64 * LD64];

  const int t = threadIdx.x;
  const int b = blockIdx.x >> 6;
  const int mt = blockIdx.x & 63;
  const long qrow0 = (long)b * 4096 + (long)mt * 64;
  const int wave = t >> 6, lane = t & 63, quad = lane >> 4, l15 = lane & 15;
  const int srow = t >> 2, sc8 = (t & 3) * 8;

  lds_st8(&Ql[srow * LD32 + sc8], *(const short8*)(Q + (qrow0 + srow) * 32 + sc8));
  __syncthreads();
  const short8 qf = lds_ld8(&Ql[(wave * 16 + l15) * LD32 + quad * 8]);

  floatx4 oacc[16];
#pragma unroll
  for (int i = 0; i < 16; i++) oacc[i] = (floatx4)0.0f;
  float mrow[4], lrow[4];
#pragma unroll
  for (int r = 0; r < 4; r++) { mrow[r] = -__builtin_inff(); lrow[r] = 0.0f; }

  const unsigned short* vsrc0 = Vt + ((long)b * 256 + t) * 4096;  // thread t = v-channel t
  const unsigned short* ksrc0 = K + (long)b * 4096 * 32;

  for (int kt = 0; kt < 64; kt++) {
    __syncthreads();
    lds_st8(&Kl[srow * LD32 + sc8], *(const short8*)(ksrc0 + (long)(kt * 64 + srow) * 32 + sc8));
    {
      const unsigned short* vs = vsrc0 + kt * 64;
#pragma unroll
      for (int c = 0; c < 8; c++)
        lds_st8(&Vl[t * LD64 + c * 8], *(const short8*)(vs + c * 8));
    }
    __syncthreads();

    // S = Q K^T : wave w computes rows [16w,16w+16) x 64 cols
    floatx4 s[4];
#pragma unroll
    for (int tn = 0; tn < 4; tn++) {
      s[tn] = (floatx4)0.0f;
      const short8 kb = lds_ld8(&Kl[(tn * 16 + l15) * LD32 + quad * 8]);
      s[tn] = MFMA16(qf, kb, s[tn]);
    }

    // online softmax per row (row = 16w + quad*4 + r; 64 cols live in this quad)
    float alpha[4];
#pragma unroll
    for (int r = 0; r < 4; r++) {
      float rm = fmaxf(fmaxf(s[0][r], s[1][r]), fmaxf(s[2][r], s[3][r]));
#pragma unroll
      for (int off = 1; off < 16; off <<= 1) rm = fmaxf(rm, __shfl_xor(rm, off));
      const float mnew = fmaxf(mrow[r], rm);
      alpha[r] = __expf(mrow[r] - mnew);  // exp(-inf)=0 on first tile
      mrow[r] = mnew;
      float rs = 0.0f;
#pragma unroll
      for (int tn = 0; tn < 4; tn++) {
        const float p = __expf(s[tn][r] - mnew);
        rs += p;
        Pl[(wave * 16 + quad * 4 + r) * LD64 + tn * 16 + l15] = f2bf(p);
      }
#pragma unroll
      for (int off = 1; off < 16; off <<= 1) rs += __shfl_xor(rs, off);
      lrow[r] = lrow[r] * alpha[r] + rs;
    }
#pragma unroll
    for (int tv = 0; tv < 16; tv++) {
#pragma unroll
      for (int r = 0; r < 4; r++) oacc[tv][r] *= alpha[r];
    }

    // P (C-layout) was spilled to LDS by this same wave; read back as A-frags.
    const short8 pa0 = lds_ld8(&Pl[(wave * 16 + l15) * LD64 + quad * 8]);
    const short8 pa1 = lds_ld8(&Pl[(wave * 16 + l15) * LD64 + 32 + quad * 8]);
#pragma unroll
    for (int tv = 0; tv < 16; tv++) {
      const short8 vb0 = lds_ld8(&Vl[(tv * 16 + l15) * LD64 + quad * 8]);
      const short8 vb1 = lds_ld8(&Vl[(tv * 16 + l15) * LD64 + 32 + quad * 8]);
      oacc[tv] = MFMA16(pa0, vb0, oacc[tv]);
      oacc[tv] = MFMA16(pa1, vb1, oacc[tv]);
    }
  }

  float inv[4];
#pragma unroll
  for (int r = 0; r < 4; r++) inv[r] = 1.0f / lrow[r];
#pragma unroll
  for (int tv = 0; tv < 16; tv++) {
#pragma unroll
    for (int r = 0; r < 4; r++) {
      const long row = qrow0 + wave * 16 + quad * 4 + r;
      O[row * 256 + tv * 16 + l15] = f2bf(oacc[tv][r] * inv[r]);
    }
  }
}

// ---------------------------------------------------------------------------
// Kernel 3: out = relu(O @ Wo + bo) + inputs  -> d_out (flag dtype)
// ---------------------------------------------------------------------------
__global__ __launch_bounds__(256)
void outp_kernel(const unsigned short* __restrict__ A,
                 const void* __restrict__ Wo, const void* __restrict__ bo,
                 const void* __restrict__ xin, void* __restrict__ out,
                 const int* __restrict__ flag) {
  __shared__ unsigned short Al[64 * LD32];
  __shared__ unsigned short Bl[64 * LD32];
  const int isf32 = *flag;
  const int t = threadIdx.x;
  const int ct = (int)(blockIdx.x & 3u);
  const long row_base = (long)(blockIdx.x >> 2) * 64;
  const int wave = t >> 6, lane = t & 63, quad = lane >> 4, l15 = lane & 15;
  const int srow = t >> 2, sc8 = (t & 3) * 8;
  const int gcol = ct * 64 + srow;

  floatx4 acc[4];
  acc[0] = acc[1] = acc[2] = acc[3] = (floatx4)0.0f;

  for (int ks = 0; ks < 8; ks++) {
    __syncthreads();
    lds_st8(&Al[srow * LD32 + sc8],
            *(const short8*)(A + (row_base + srow) * 256 + ks * 32 + sc8));
    {
      short8 v;
#pragma unroll
      for (int j = 0; j < 8; j++)
        v[j] = (short)f2bf(ld_in(Wo, (long)(ks * 32 + sc8 + j) * 256 + gcol, isf32));
      lds_st8(&Bl[srow * LD32 + sc8], v);
    }
    __syncthreads();
    const short8 a = lds_ld8(&Al[(wave * 16 + l15) * LD32 + quad * 8]);
#pragma unroll
    for (int tn = 0; tn < 4; tn++) {
      const short8 bfr = lds_ld8(&Bl[(tn * 16 + l15) * LD32 + quad * 8]);
      acc[tn] = MFMA16(a, bfr, acc[tn]);
    }
  }

#pragma unroll
  for (int tn = 0; tn < 4; tn++) {
    const int g = ct * 64 + tn * 16 + l15;
    const float bias = ld_in(bo, g, isf32);
#pragma unroll
    for (int r = 0; r < 4; r++) {
      const long row = row_base + wave * 16 + quad * 4 + r;
      const long gi = row * 256 + g;
      float vv = fmaxf(acc[tn][r] + bias, 0.0f);
      vv += ld_in(xin, gi, isf32);
      if (isf32) ((float*)out)[gi] = vv;
      else ((unsigned short*)out)[gi] = f2bf(vv);
    }
  }
}

extern "C" void kernel_launch(void* const* d_in, const int* in_sizes, int n_in,
                              void* d_out, int out_size, void* d_ws, size_t ws_size,
                              hipStream_t stream) {
  const void* x  = d_in[0];
  const void* Wq = d_in[1]; const void* bq = d_in[2];
  const void* Wk = d_in[3]; const void* bk = d_in[4];
  const void* Wv = d_in[5]; const void* bv = d_in[6];
  const void* Wo = d_in[7]; const void* bo = d_in[8];

  char* ws = (char*)d_ws;
  int* flag = (int*)ws;
  unsigned short* Q  = (unsigned short*)(ws + 256);
  unsigned short* K  = Q + (long)4 * 4096 * 32;       // 1 MB each
  unsigned short* Vt = K + (long)4 * 4096 * 32;       // 8 MB
  unsigned short* O  = Vt + (long)4 * 256 * 4096;     // 8 MB

  detect_kernel<<<1, 64, 0, stream>>>((const unsigned short*)x, flag);
  proj_kernel<<<1280, 256, 0, stream>>>(x, Wq, bq, Wk, bk, Wv, bv, Q, K, Vt, flag);
  flash_kernel<<<256, 256, 0, stream>>>(Q, K, Vt, O);
  outp_kernel<<<1024, 256, 0, stream>>>(O, Wo, bo, x, d_out, flag);
}

// Round 2
// 258.799 us; speedup vs baseline: 1.2557x; 1.2557x over previous
//
#include <hip/hip_runtime.h>

typedef __attribute__((ext_vector_type(8))) short short8;
typedef __attribute__((ext_vector_type(4))) short short4v;
typedef __attribute__((ext_vector_type(4))) float floatx4;

#define MFMA16(a, b, c) __builtin_amdgcn_mfma_f32_16x16x32_bf16((a), (b), (c), 0, 0, 0)

#define LD64 68    // Pl row stride (elems): 8B-aligned frags, no extra bank conflicts
#define LDO  272   // Ol row stride (elems): 16B-aligned rows, 2-way banks (free)

__device__ __forceinline__ float bf2f(unsigned short u) {
  return __uint_as_float(((unsigned int)u) << 16);
}
__device__ __forceinline__ unsigned short f2bf(float f) {
  unsigned int x = __float_as_uint(f);
  x += 0x7FFFu + ((x >> 16) & 1u);   // RNE; finite inputs
  return (unsigned short)(x >> 16);
}
__device__ __forceinline__ float ld_in(const void* p, long i, int isf32) {
  if (isf32) return ((const float*)p)[i];
  return bf2f(((const unsigned short*)p)[i]);
}
__device__ __forceinline__ short8 lds_ld8(const unsigned short* p) {
  short4v a = *(const short4v*)p;
  short4v b = *(const short4v*)(p + 4);
  return __builtin_shufflevector(a, b, 0, 1, 2, 3, 4, 5, 6, 7);
}
__device__ __forceinline__ short8 g_ld8(const unsigned short* p) {
  return *(const short8*)p;   // 16B-aligned global vector load
}

// ---------------------------------------------------------------------------
// Kernel 0: dtype detect (fp32 vs bf16), as R1 (verified working).
// ---------------------------------------------------------------------------
__global__ void detect_kernel(const unsigned short* __restrict__ in0, int* __restrict__ flag) {
  int t = threadIdx.x;  // 64 threads
  int bad = 0;
  for (int i = t; i < 4096; i += 64) {
    unsigned int e = (in0[i] >> 7) & 0xFFu;
    if (e >= 141u) bad = 1;
  }
  unsigned long long m = __ballot(bad);
  if (t == 0) *flag = (m != 0ull) ? 1 : 0;
}

// ---------------------------------------------------------------------------
// Kernel 1: weight prep. Wt_qkv[320][256] bf16 = [Wq|Wk|Wv]^T, Wt_o[256][256]
// bf16 = Wo^T, biases to f32. Transposed layout makes every GEMM B-fragment a
// coalesced 16B load.
// ---------------------------------------------------------------------------
__global__ __launch_bounds__(256)
void prep_kernel(const void* __restrict__ Wq, const void* __restrict__ bq,
                 const void* __restrict__ Wk, const void* __restrict__ bk,
                 const void* __restrict__ Wv, const void* __restrict__ bv,
                 const void* __restrict__ Wo, const void* __restrict__ bo,
                 unsigned short* __restrict__ Wt_qkv, unsigned short* __restrict__ Wt_o,
                 float* __restrict__ b_qkv, float* __restrict__ b_o,
                 const int* __restrict__ flag) {
  const int isf32 = *flag;
  const int g = (int)blockIdx.x, c = (int)threadIdx.x;
  if (g < 320) {
    float v;
    if (g < 32)      v = ld_in(Wq, (long)c * 32 + g, isf32);
    else if (g < 64) v = ld_in(Wk, (long)c * 32 + (g - 32), isf32);
    else             v = ld_in(Wv, (long)c * 256 + (g - 64), isf32);
    Wt_qkv[g * 256 + c] = f2bf(v);
  } else if (g < 576) {
    const int go = g - 320;
    Wt_o[go * 256 + c] = f2bf(ld_in(Wo, (long)c * 256 + go, isf32));
  } else if (g == 576) {
    for (int i = c; i < 320; i += 256) {
      float v = (i < 32) ? ld_in(bq, i, isf32)
              : (i < 64) ? ld_in(bk, i - 32, isf32)
                         : ld_in(bv, i - 64, isf32);
      b_qkv[i] = v;
    }
  } else {
    b_o[c] = ld_in(bo, c, isf32);
  }
}

// ---------------------------------------------------------------------------
// Kernel 2: QKV projection — LDS-free, barrier-free streaming MFMA GEMM.
// grid = 256 row-tiles x 5 col-tiles. ct0: q|k cols (64), ct1-4: v cols.
// A frag: x[(row)*256 + k] direct 16B; B frag: Wt_qkv[g][k] direct 16B.
// Q,K row-major bf16 [B*4096,32]; V transposed: Vt[b][ch][n] bf16.
// ---------------------------------------------------------------------------
__global__ __launch_bounds__(256)
void proj_kernel(const void* __restrict__ x, const unsigned short* __restrict__ Wt,
                 const float* __restrict__ b_qkv,
                 unsigned short* __restrict__ Q, unsigned short* __restrict__ Kk,
                 unsigned short* __restrict__ Vt, const int* __restrict__ flag) {
  const int isf32 = *flag;
  const int t = threadIdx.x;
  const int ct = (int)(blockIdx.x % 5u);
  const long row_base = (long)(blockIdx.x / 5u) * 64;
  const int wave = t >> 6, lane = t & 63, quad = lane >> 4, l15 = lane & 15;
  const long arow = row_base + wave * 16 + l15;

  floatx4 acc[4];
  acc[0] = acc[1] = acc[2] = acc[3] = (floatx4)0.0f;

#pragma unroll
  for (int ks = 0; ks < 8; ks++) {
    short8 a;
    if (isf32) {
      const float* xf = (const float*)x + arow * 256 + ks * 32 + quad * 8;
      floatx4 f0 = *(const floatx4*)xf;
      floatx4 f1 = *(const floatx4*)(xf + 4);
#pragma unroll
      for (int j = 0; j < 4; j++) { a[j] = (short)f2bf(f0[j]); a[4 + j] = (short)f2bf(f1[j]); }
    } else {
      a = g_ld8((const unsigned short*)x + arow * 256 + ks * 32 + quad * 8);
    }
#pragma unroll
    for (int tn = 0; tn < 4; tn++) {
      const short8 bfr = g_ld8(Wt + (long)(ct * 64 + tn * 16 + l15) * 256 + ks * 32 + quad * 8);
      acc[tn] = MFMA16(a, bfr, acc[tn]);
    }
  }

#pragma unroll
  for (int tn = 0; tn < 4; tn++) {
    const int g = ct * 64 + tn * 16 + l15;
    const float bias = b_qkv[g];
#pragma unroll
    for (int r = 0; r < 4; r++) {
      const long row = row_base + wave * 16 + quad * 4 + r;  // = b*4096 + n
      const unsigned short h = f2bf(fmaxf(acc[tn][r] + bias, 0.0f));
      if (g < 32)      Q[row * 32 + g] = h;
      else if (g < 64) Kk[row * 32 + (g - 32)] = h;
      else             Vt[((row >> 12) * 256 + (long)(g - 64)) * 4096 + (row & 4095)] = h;
    }
  }
}

// ---------------------------------------------------------------------------
// Kernel 3: flash attention + FUSED out-projection + residual.
// 256 blocks (batch x 64-row Q tile) x 512 threads (8 waves).
//   Waves 0-3: S = Q K^T for rows [16w,16w+16), online softmax, publish
//              P (bf16, LDS) and alpha (LDS).
//   All 8 waves: PV with channel split — wave w owns v-channels [32w,32w+32);
//              V B-frags read DIRECT from global Vt (L2-hot), P A-frags from LDS.
// Epilogue: normalized O tile -> LDS, then per-wave MFMA GEMM vs Wt_o with
// bias+relu+residual, store d_out in detected dtype.
// ---------------------------------------------------------------------------
__global__ __launch_bounds__(512)
void flash_kernel(const unsigned short* __restrict__ Q,
                  const unsigned short* __restrict__ K,
                  const unsigned short* __restrict__ Vt,
                  const unsigned short* __restrict__ Wt_o,
                  const float* __restrict__ b_o,
                  const void* __restrict__ xin, void* __restrict__ out,
                  const int* __restrict__ flag) {
  __shared__ unsigned short Pl[64 * LD64];
  __shared__ unsigned short Ol[64 * LDO];
  __shared__ float Al[64];
  __shared__ float Ll[64];

  const int t = threadIdx.x;
  const int b = (int)(blockIdx.x >> 6), mt = (int)(blockIdx.x & 63u);
  const long qrow0 = (long)b * 4096 + (long)mt * 64;
  const int wave = t >> 6, lane = t & 63, quad = lane >> 4, l15 = lane & 15;

  // V channel owned by this lane for PV B-frags (tv selects +0/+16)
  const unsigned short* vbase = Vt + ((long)b * 256 + wave * 32 + l15) * 4096;
  const unsigned short* kbase = K + (long)b * 4096 * 32;

  short8 qf, kb[4];
  if (wave < 4) {
    qf = g_ld8(Q + (qrow0 + wave * 16 + l15) * 32 + quad * 8);
#pragma unroll
    for (int tn = 0; tn < 4; tn++)
      kb[tn] = g_ld8(kbase + (long)(tn * 16 + l15) * 32 + quad * 8);  // kt=0
  }

  floatx4 oacc[4][2];
#pragma unroll
  for (int m = 0; m < 4; m++) { oacc[m][0] = (floatx4)0.0f; oacc[m][1] = (floatx4)0.0f; }
  float mrow[4], lrow[4];
#pragma unroll
  for (int r = 0; r < 4; r++) { mrow[r] = -__builtin_inff(); lrow[r] = 0.0f; }

  for (int kt = 0; kt < 64; kt++) {
    // prefetch this tile's V B-frags (consumed after the barrier)
    short8 vb[2][2];
#pragma unroll
    for (int tv = 0; tv < 2; tv++)
#pragma unroll
      for (int kh = 0; kh < 2; kh++)
        vb[tv][kh] = g_ld8(vbase + (long)tv * 16 * 4096 + kt * 64 + kh * 32 + quad * 8);

    if (wave < 4) {
      floatx4 s[4];
#pragma unroll
      for (int tn = 0; tn < 4; tn++) { s[tn] = (floatx4)0.0f; s[tn] = MFMA16(qf, kb[tn], s[tn]); }
      // prefetch next tile's K B-frags (wraps harmlessly at kt=63)
      const int ktn = (kt + 1) & 63;
#pragma unroll
      for (int tn = 0; tn < 4; tn++)
        kb[tn] = g_ld8(kbase + (long)(ktn * 64 + tn * 16 + l15) * 32 + quad * 8);

      floatx4 aw;
#pragma unroll
      for (int r = 0; r < 4; r++) {
        float rm = fmaxf(fmaxf(s[0][r], s[1][r]), fmaxf(s[2][r], s[3][r]));
#pragma unroll
        for (int off = 1; off < 16; off <<= 1) rm = fmaxf(rm, __shfl_xor(rm, off));
        const float mnew = fmaxf(mrow[r], rm);
        aw[r] = __expf(mrow[r] - mnew);
        mrow[r] = mnew;
        float rs = 0.0f;
#pragma unroll
        for (int tn = 0; tn < 4; tn++) {
          const float p = __expf(s[tn][r] - mnew);
          rs += p;
          Pl[(wave * 16 + quad * 4 + r) * LD64 + tn * 16 + l15] = f2bf(p);
        }
#pragma unroll
        for (int off = 1; off < 16; off <<= 1) rs += __shfl_xor(rs, off);
        lrow[r] = lrow[r] * aw[r] + rs;
      }
      if (l15 == 0) *(floatx4*)&Al[wave * 16 + quad * 4] = aw;
    }
    __syncthreads();   // publish P, alpha

    // rescale + PV (all 8 waves)
#pragma unroll
    for (int m = 0; m < 4; m++) {
      const floatx4 al = *(const floatx4*)&Al[m * 16 + quad * 4];
#pragma unroll
      for (int tv = 0; tv < 2; tv++)
#pragma unroll
        for (int r = 0; r < 4; r++) oacc[m][tv][r] *= al[r];
    }
    short8 pa[4][2];
#pragma unroll
    for (int m = 0; m < 4; m++)
#pragma unroll
      for (int kh = 0; kh < 2; kh++)
        pa[m][kh] = lds_ld8(&Pl[(m * 16 + l15) * LD64 + kh * 32 + quad * 8]);
#pragma unroll
    for (int tv = 0; tv < 2; tv++)
#pragma unroll
      for (int kh = 0; kh < 2; kh++)
#pragma unroll
        for (int m = 0; m < 4; m++)
          oacc[m][tv] = MFMA16(pa[m][kh], vb[tv][kh], oacc[m][tv]);
    __syncthreads();   // protect Pl/Al before next tile's writes
  }

  // ---- epilogue: normalize O tile into LDS ----
  if (wave < 4 && l15 == 0) {
    floatx4 lw;
#pragma unroll
    for (int r = 0; r < 4; r++) lw[r] = lrow[r];
    *(floatx4*)&Ll[wave * 16 + quad * 4] = lw;
  }
  __syncthreads();
#pragma unroll
  for (int m = 0; m < 4; m++) {
    const floatx4 ll = *(const floatx4*)&Ll[m * 16 + quad * 4];
    floatx4 inv;
#pragma unroll
    for (int r = 0; r < 4; r++) inv[r] = 1.0f / ll[r];
#pragma unroll
    for (int tv = 0; tv < 2; tv++)
#pragma unroll
      for (int r = 0; r < 4; r++)
        Ol[(m * 16 + quad * 4 + r) * LDO + wave * 32 + tv * 16 + l15] =
            f2bf(oacc[m][tv][r] * inv[r]);
  }
  __syncthreads();

  // ---- fused out-projection: wave -> (row group m2 = wave&3, col half = wave>>2)
  const int m2 = wave & 3, gh = wave >> 2;
  floatx4 acc2[8];
#pragma unroll
  for (int i = 0; i < 8; i++) acc2[i] = (floatx4)0.0f;
#pragma unroll
  for (int ks = 0; ks < 8; ks++) {
    const short8 a = lds_ld8(&Ol[(m2 * 16 + l15) * LDO + ks * 32 + quad * 8]);
#pragma unroll
    for (int tn = 0; tn < 8; tn++) {
      const short8 bfr = g_ld8(Wt_o + (long)(gh * 128 + tn * 16 + l15) * 256 + ks * 32 + quad * 8);
      acc2[tn] = MFMA16(a, bfr, acc2[tn]);
    }
  }
  const int isf32 = *flag;
#pragma unroll
  for (int tn = 0; tn < 8; tn++) {
    const int g = gh * 128 + tn * 16 + l15;
    const float bias = b_o[g];
#pragma unroll
    for (int r = 0; r < 4; r++) {
      const long row = qrow0 + m2 * 16 + quad * 4 + r;
      const long gi = row * 256 + g;
      const float vv = fmaxf(acc2[tn][r] + bias, 0.0f) + ld_in(xin, gi, isf32);
      if (isf32) ((float*)out)[gi] = vv;
      else       ((unsigned short*)out)[gi] = f2bf(vv);
    }
  }
}

extern "C" void kernel_launch(void* const* d_in, const int* in_sizes, int n_in,
                              void* d_out, int out_size, void* d_ws, size_t ws_size,
                              hipStream_t stream) {
  const void* x  = d_in[0];
  const void* Wq = d_in[1]; const void* bq = d_in[2];
  const void* Wk = d_in[3]; const void* bk = d_in[4];
  const void* Wv = d_in[5]; const void* bv = d_in[6];
  const void* Wo = d_in[7]; const void* bo = d_in[8];

  char* ws = (char*)d_ws;
  int*            flag   = (int*)ws;                                   // 256 B
  unsigned short* Wt_qkv = (unsigned short*)(ws + 256);                // 160 KB
  unsigned short* Wt_o   = (unsigned short*)(ws + 164096);             // 128 KB
  float*          b_qkv  = (float*)(ws + 295168);                      // 1.25 KB
  float*          b_o    = (float*)(ws + 296448);                      // 1 KB
  unsigned short* Q      = (unsigned short*)(ws + 297472);             // 1 MB
  unsigned short* K      = Q + (long)4 * 4096 * 32;                    // 1 MB
  unsigned short* Vt     = K + (long)4 * 4096 * 32;                    // 8 MB
  // total ~10.3 MB (< R1's 18.25 MB which fit)

  detect_kernel<<<1, 64, 0, stream>>>((const unsigned short*)x, flag);
  prep_kernel<<<578, 256, 0, stream>>>(Wq, bq, Wk, bk, Wv, bv, Wo, bo,
                                       Wt_qkv, Wt_o, b_qkv, b_o, flag);
  proj_kernel<<<1280, 256, 0, stream>>>(x, Wt_qkv, b_qkv, Q, K, Vt, flag);
  flash_kernel<<<256, 512, 0, stream>>>(Q, K, Vt, Wt_o, b_o, x, d_out, flag);
}

// Round 3
// 221.967 us; speedup vs baseline: 1.4641x; 1.1659x over previous
//
#include <hip/hip_runtime.h>

typedef __attribute__((ext_vector_type(8))) short short8;
typedef __attribute__((ext_vector_type(4))) float floatx4;

#define MFMA16(a, b, c) __builtin_amdgcn_mfma_f32_16x16x32_bf16((a), (b), (c), 0, 0, 0)

#define LDP 72     // P/V-tile LDS row stride: 16B-aligned rows, balanced banks (72*2=144B)
#define LDO 272    // O-tile LDS row stride: 16B-aligned rows (544B)
#define SHIFT 16.0f  // constant exp shift; scores >= 0 always (relu*relu sums)

__device__ __forceinline__ float bf2f(unsigned short u) {
  return __uint_as_float(((unsigned int)u) << 16);
}
__device__ __forceinline__ unsigned short f2bf(float f) {
  unsigned int x = __float_as_uint(f);
  x += 0x7FFFu + ((x >> 16) & 1u);   // RNE; finite inputs
  return (unsigned short)(x >> 16);
}
__device__ __forceinline__ float ld_in(const void* p, long i, int isf32) {
  if (isf32) return ((const float*)p)[i];
  return bf2f(((const unsigned short*)p)[i]);
}
// all call sites are 16B-aligned by construction -> ds_read_b128 / global x4
__device__ __forceinline__ short8 ld16(const unsigned short* p) {
  return *(const short8*)__builtin_assume_aligned(p, 16);
}
__device__ __forceinline__ void st16(unsigned short* p, short8 v) {
  *(short8*)__builtin_assume_aligned(p, 16) = v;
}

// ---------------------------------------------------------------------------
// Kernel 0: dtype detect (fp32 vs bf16) — verified in R1/R2.
// ---------------------------------------------------------------------------
__global__ void detect_kernel(const unsigned short* __restrict__ in0, int* __restrict__ flag) {
  int t = threadIdx.x;
  int bad = 0;
  for (int i = t; i < 4096; i += 64) {
    unsigned int e = (in0[i] >> 7) & 0xFFu;
    if (e >= 141u) bad = 1;
  }
  unsigned long long m = __ballot(bad);
  if (t == 0) *flag = (m != 0ull) ? 1 : 0;
}

// ---------------------------------------------------------------------------
// Kernel 1: weight prep -> bf16 transposed weights + f32 biases.
// ---------------------------------------------------------------------------
__global__ __launch_bounds__(256)
void prep_kernel(const void* __restrict__ Wq, const void* __restrict__ bq,
                 const void* __restrict__ Wk, const void* __restrict__ bk,
                 const void* __restrict__ Wv, const void* __restrict__ bv,
                 const void* __restrict__ Wo, const void* __restrict__ bo,
                 unsigned short* __restrict__ Wt_qkv, unsigned short* __restrict__ Wt_o,
                 float* __restrict__ b_qkv, float* __restrict__ b_o,
                 const int* __restrict__ flag) {
  const int isf32 = *flag;
  const int g = (int)blockIdx.x, c = (int)threadIdx.x;
  if (g < 320) {
    float v;
    if (g < 32)      v = ld_in(Wq, (long)c * 32 + g, isf32);
    else if (g < 64) v = ld_in(Wk, (long)c * 32 + (g - 32), isf32);
    else             v = ld_in(Wv, (long)c * 256 + (g - 64), isf32);
    Wt_qkv[g * 256 + c] = f2bf(v);
  } else if (g < 576) {
    const int go = g - 320;
    Wt_o[go * 256 + c] = f2bf(ld_in(Wo, (long)c * 256 + go, isf32));
  } else if (g == 576) {
    for (int i = c; i < 320; i += 256) {
      float v = (i < 32) ? ld_in(bq, i, isf32)
              : (i < 64) ? ld_in(bk, i - 32, isf32)
                         : ld_in(bv, i - 64, isf32);
      b_qkv[i] = v;
    }
  } else {
    b_o[c] = ld_in(bo, c, isf32);
  }
}

// ---------------------------------------------------------------------------
// Kernel 2: QKV projection. Streaming MFMA GEMM, LDS-free main loop.
// ct0 -> Q|K (64 cols); ct1-4 -> V (64 cols each), transposed through LDS so
// Vt[b][ch][n] stores are coalesced 16B vectors (R2 did 4M scalar 8KB-strided
// 2B stores — the suspected ~100us of the non-flash gap).
// ---------------------------------------------------------------------------
__global__ __launch_bounds__(256)
void proj_kernel(const void* __restrict__ x, const unsigned short* __restrict__ Wt,
                 const float* __restrict__ b_qkv,
                 unsigned short* __restrict__ Q, unsigned short* __restrict__ Kk,
                 unsigned short* __restrict__ Vt, const int* __restrict__ flag) {
  __shared__ unsigned short Vl[64 * LDP];
  const int isf32 = *flag;
  const int t = threadIdx.x;
  const int ct = (int)(blockIdx.x % 5u);
  const long row_base = (long)(blockIdx.x / 5u) * 64;
  const int wave = t >> 6, lane = t & 63, quad = lane >> 4, l15 = lane & 15;
  const long arow = row_base + wave * 16 + l15;

  floatx4 acc[4];
  acc[0] = acc[1] = acc[2] = acc[3] = (floatx4)0.0f;

#pragma unroll
  for (int ks = 0; ks < 8; ks++) {
    short8 a;
    if (isf32) {
      const float* xf = (const float*)x + arow * 256 + ks * 32 + quad * 8;
      floatx4 f0 = *(const floatx4*)xf;
      floatx4 f1 = *(const floatx4*)(xf + 4);
#pragma unroll
      for (int j = 0; j < 4; j++) { a[j] = (short)f2bf(f0[j]); a[4 + j] = (short)f2bf(f1[j]); }
    } else {
      a = ld16((const unsigned short*)x + arow * 256 + ks * 32 + quad * 8);
    }
#pragma unroll
    for (int tn = 0; tn < 4; tn++) {
      const short8 bfr = ld16(Wt + (long)(ct * 64 + tn * 16 + l15) * 256 + ks * 32 + quad * 8);
      acc[tn] = MFMA16(a, bfr, acc[tn]);
    }
  }

  if (ct == 0) {
#pragma unroll
    for (int tn = 0; tn < 4; tn++) {
      const int g = tn * 16 + l15;
      const float bias = b_qkv[g];
#pragma unroll
      for (int r = 0; r < 4; r++) {
        const long row = row_base + wave * 16 + quad * 4 + r;
        const unsigned short h = f2bf(fmaxf(acc[tn][r] + bias, 0.0f));
        if (g < 32) Q[row * 32 + g] = h;
        else        Kk[row * 32 + (g - 32)] = h;
      }
    }
  } else {
    // V: acc -> LDS[ch_local][n_local], then coalesced 16B stores to Vt
#pragma unroll
    for (int tn = 0; tn < 4; tn++) {
      const float bias = b_qkv[ct * 64 + tn * 16 + l15];
#pragma unroll
      for (int r = 0; r < 4; r++)
        Vl[(tn * 16 + l15) * LDP + wave * 16 + quad * 4 + r] =
            f2bf(fmaxf(acc[tn][r] + bias, 0.0f));
    }
    __syncthreads();
    const int chl = t >> 2, nc = (t & 3) * 16;
    const long bb = row_base >> 12, n0 = row_base & 4095;
    unsigned short* dst = Vt + (bb * 256 + (long)(ct - 1) * 64 + chl) * 4096 + n0 + nc;
    st16(dst,     ld16(&Vl[chl * LDP + nc]));
    st16(dst + 8, ld16(&Vl[chl * LDP + nc + 8]));
  }
}

// ---------------------------------------------------------------------------
// Kernel 3: flash attention (no-max: scores >= 0, exp(s-16)) + fused out-proj.
// 256 blocks (batch-XCD-swizzled) x 512 threads (8 waves), 64-row Q tiles.
// Per tile (single barrier, double-buffered Pl):
//   all 8 waves: S tile 16rows x 32cols (wave = rowblock w&3, colhalf w>>2),
//   exp + bf16 P store + per-lane l partial; BARRIER;
//   all 8 waves: PV channel-split (32 ch/wave), P A-frags ds_read_b128,
//   V B-frags direct-from-global (L2-hot, prefetched one tile ahead).
// l reduced once at the end. Epilogue: Ol -> MFMA out-proj + bias/relu/residual.
// ---------------------------------------------------------------------------
__global__ __launch_bounds__(512)
void flash_kernel(const unsigned short* __restrict__ Q,
                  const unsigned short* __restrict__ K,
                  const unsigned short* __restrict__ Vt,
                  const unsigned short* __restrict__ Wt_o,
                  const float* __restrict__ b_o,
                  const void* __restrict__ xin, void* __restrict__ out,
                  const int* __restrict__ flag) {
  __shared__ unsigned short Pl[2][64 * LDP];   // 18.4 KB
  __shared__ unsigned short Ol[64 * LDO];      // 34.8 KB
  __shared__ float Lp[2][64];
  __shared__ float Ll[64];

  const int t = threadIdx.x;
  // batch->XCD swizzle: batch b lives on XCDs {b, b+4} -> 2.25MB working set/XCD
  const int raw = (int)blockIdx.x;
  const int x8 = raw & 7;
  const int b = x8 & 3;
  const int mt = (raw >> 3) | ((x8 >> 2) << 5);
  const long qrow0 = (long)b * 4096 + (long)mt * 64;
  const int wave = t >> 6, lane = t & 63, quad = lane >> 4, l15 = lane & 15;
  const int m = wave & 3, h = wave >> 2;   // QK: rows [16m,16m+16), cols [32h,32h+32)

  const unsigned short* vbase = Vt + ((long)b * 256 + wave * 32 + l15) * 4096;
  const unsigned short* kbase = K + (long)b * 4096 * 32;

  const short8 qf = ld16(Q + (qrow0 + m * 16 + l15) * 32 + quad * 8);
  short8 kb[2];
#pragma unroll
  for (int i = 0; i < 2; i++)
    kb[i] = ld16(kbase + (long)((h * 2 + i) * 16 + l15) * 32 + quad * 8);
  short8 vb[2][2];
#pragma unroll
  for (int tv = 0; tv < 2; tv++)
#pragma unroll
    for (int kh = 0; kh < 2; kh++)
      vb[tv][kh] = ld16(vbase + (long)tv * 16 * 4096 + kh * 32 + quad * 8);

  floatx4 oacc[4][2];
#pragma unroll
  for (int i = 0; i < 4; i++) { oacc[i][0] = (floatx4)0.0f; oacc[i][1] = (floatx4)0.0f; }
  float lpart[4] = {0.0f, 0.0f, 0.0f, 0.0f};

  for (int kt = 0; kt < 64; kt++) {
    // S tile: 2 MFMA
    floatx4 s[2];
#pragma unroll
    for (int i = 0; i < 2; i++) { s[i] = (floatx4)0.0f; s[i] = MFMA16(qf, kb[i], s[i]); }
    // prefetch next K frags
    const int ktn = (kt + 1) & 63;
#pragma unroll
    for (int i = 0; i < 2; i++)
      kb[i] = ld16(kbase + (long)(ktn * 64 + (h * 2 + i) * 16 + l15) * 32 + quad * 8);

    // exp + P store + l partial (no max tracking: s >= 0, shift is constant)
    unsigned short* pl = Pl[kt & 1];
#pragma unroll
    for (int i = 0; i < 2; i++)
#pragma unroll
      for (int r = 0; r < 4; r++) {
        const float p = __expf(s[i][r] - SHIFT);
        lpart[r] += p;
        pl[(m * 16 + quad * 4 + r) * LDP + (h * 2 + i) * 16 + l15] = f2bf(p);
      }
    __syncthreads();   // publish P(kt); next write targets Pl[(kt+1)&1] -> safe

    // prefetch next V frags (consumed next iteration)
    short8 vbn[2][2];
#pragma unroll
    for (int tv = 0; tv < 2; tv++)
#pragma unroll
      for (int kh = 0; kh < 2; kh++)
        vbn[tv][kh] = ld16(vbase + (long)tv * 16 * 4096 + ktn * 64 + kh * 32 + quad * 8);

    // P A-frags: 8x ds_read_b128, balanced banks
    const unsigned short* plr = Pl[kt & 1];
    short8 pa[4][2];
#pragma unroll
    for (int mm = 0; mm < 4; mm++)
#pragma unroll
      for (int kh = 0; kh < 2; kh++)
        pa[mm][kh] = ld16(&plr[(mm * 16 + l15) * LDP + kh * 32 + quad * 8]);

#pragma unroll
    for (int tv = 0; tv < 2; tv++)
#pragma unroll
      for (int kh = 0; kh < 2; kh++)
#pragma unroll
        for (int mm = 0; mm < 4; mm++)
          oacc[mm][tv] = MFMA16(pa[mm][kh], vb[tv][kh], oacc[mm][tv]);

#pragma unroll
    for (int tv = 0; tv < 2; tv++)
#pragma unroll
      for (int kh = 0; kh < 2; kh++)
        vb[tv][kh] = vbn[tv][kh];
  }

  // ---- deferred l reduction: 16-lane shuffle + cross-colhalf combine ----
#pragma unroll
  for (int r = 0; r < 4; r++)
#pragma unroll
    for (int off = 1; off < 16; off <<= 1)
      lpart[r] += __shfl_xor(lpart[r], off);
  if (l15 == 0) {
    floatx4 lw;
#pragma unroll
    for (int r = 0; r < 4; r++) lw[r] = lpart[r];
    *(floatx4*)&Lp[h][m * 16 + quad * 4] = lw;
  }
  __syncthreads();
  if (t < 64) Ll[t] = 1.0f / (Lp[0][t] + Lp[1][t]);
  __syncthreads();

  // ---- normalize into Ol ----
#pragma unroll
  for (int mm = 0; mm < 4; mm++) {
    const floatx4 ll = *(const floatx4*)&Ll[mm * 16 + quad * 4];
#pragma unroll
    for (int tv = 0; tv < 2; tv++)
#pragma unroll
      for (int r = 0; r < 4; r++)
        Ol[(mm * 16 + quad * 4 + r) * LDO + wave * 32 + tv * 16 + l15] =
            f2bf(oacc[mm][tv][r] * ll[r]);
  }
  __syncthreads();

  // ---- fused out-projection + bias + relu + residual ----
  const int m2 = wave & 3, gh = wave >> 2;
  floatx4 acc2[8];
#pragma unroll
  for (int i = 0; i < 8; i++) acc2[i] = (floatx4)0.0f;
#pragma unroll
  for (int ks = 0; ks < 8; ks++) {
    const short8 a = ld16(&Ol[(m2 * 16 + l15) * LDO + ks * 32 + quad * 8]);
#pragma unroll
    for (int tn = 0; tn < 8; tn++) {
      const short8 bfr = ld16(Wt_o + (long)(gh * 128 + tn * 16 + l15) * 256 + ks * 32 + quad * 8);
      acc2[tn] = MFMA16(a, bfr, acc2[tn]);
    }
  }
  const int isf32 = *flag;
#pragma unroll
  for (int tn = 0; tn < 8; tn++) {
    const int g = gh * 128 + tn * 16 + l15;
    const float bias = b_o[g];
#pragma unroll
    for (int r = 0; r < 4; r++) {
      const long row = qrow0 + m2 * 16 + quad * 4 + r;
      const long gi = row * 256 + g;
      const float vv = fmaxf(acc2[tn][r] + bias, 0.0f) + ld_in(xin, gi, isf32);
      if (isf32) ((float*)out)[gi] = vv;
      else       ((unsigned short*)out)[gi] = f2bf(vv);
    }
  }
}

extern "C" void kernel_launch(void* const* d_in, const int* in_sizes, int n_in,
                              void* d_out, int out_size, void* d_ws, size_t ws_size,
                              hipStream_t stream) {
  const void* x  = d_in[0];
  const void* Wq = d_in[1]; const void* bq = d_in[2];
  const void* Wk = d_in[3]; const void* bk = d_in[4];
  const void* Wv = d_in[5]; const void* bv = d_in[6];
  const void* Wo = d_in[7]; const void* bo = d_in[8];

  char* ws = (char*)d_ws;
  int*            flag   = (int*)ws;                                   // 256 B
  unsigned short* Wt_qkv = (unsigned short*)(ws + 256);                // 160 KB
  unsigned short* Wt_o   = (unsigned short*)(ws + 164096);             // 128 KB
  float*          b_qkv  = (float*)(ws + 295168);                      // 1.25 KB
  float*          b_o    = (float*)(ws + 296448);                      // 1 KB
  unsigned short* Q      = (unsigned short*)(ws + 297472);             // 1 MB
  unsigned short* K      = Q + (long)4 * 4096 * 32;                    // 1 MB
  unsigned short* Vt     = K + (long)4 * 4096 * 32;                    // 8 MB

  detect_kernel<<<1, 64, 0, stream>>>((const unsigned short*)x, flag);
  prep_kernel<<<578, 256, 0, stream>>>(Wq, bq, Wk, bk, Wv, bv, Wo, bo,
                                       Wt_qkv, Wt_o, b_qkv, b_o, flag);
  proj_kernel<<<1280, 256, 0, stream>>>(x, Wt_qkv, b_qkv, Q, K, Vt, flag);
  flash_kernel<<<256, 512, 0, stream>>>(Q, K, Vt, Wt_o, b_o, x, d_out, flag);
}

// Round 4
// 215.550 us; speedup vs baseline: 1.5077x; 1.0298x over previous
//
#include <hip/hip_runtime.h>

typedef __attribute__((ext_vector_type(8))) short short8;
typedef __attribute__((ext_vector_type(4))) float floatx4;

#define MFMA16(a, b, c) __builtin_amdgcn_mfma_f32_16x16x32_bf16((a), (b), (c), 0, 0, 0)

#define LDP 72     // P LDS row stride: 144B rows -> 16B-aligned b128 frags
#define LDO 272    // O-tile LDS row stride
#define SHIFT 16.0f  // constant exp shift; scores >= 0 (relu*relu sums)

__device__ __forceinline__ float bf2f(unsigned short u) {
  return __uint_as_float(((unsigned int)u) << 16);
}
__device__ __forceinline__ unsigned short f2bf(float f) {
  unsigned int x = __float_as_uint(f);
  x += 0x7FFFu + ((x >> 16) & 1u);   // RNE; finite inputs
  return (unsigned short)(x >> 16);
}
__device__ __forceinline__ float ld_in(const void* p, long i, int isf32) {
  if (isf32) return ((const float*)p)[i];
  return bf2f(((const unsigned short*)p)[i]);
}
__device__ __forceinline__ short8 ld16(const unsigned short* p) {
  return *(const short8*)__builtin_assume_aligned(p, 16);
}
__device__ __forceinline__ void st16(unsigned short* p, short8 v) {
  *(short8*)__builtin_assume_aligned(p, 16) = v;
}

// ---------------------------------------------------------------------------
// Kernel 0: dtype detect (fp32 vs bf16) — verified R1-R3.
// ---------------------------------------------------------------------------
__global__ void detect_kernel(const unsigned short* __restrict__ in0, int* __restrict__ flag) {
  int t = threadIdx.x;
  int bad = 0;
  for (int i = t; i < 4096; i += 64) {
    unsigned int e = (in0[i] >> 7) & 0xFFu;
    if (e >= 141u) bad = 1;
  }
  unsigned long long m = __ballot(bad);
  if (t == 0) *flag = (m != 0ull) ? 1 : 0;
}

// ---------------------------------------------------------------------------
// Kernel 1: weight prep -> bf16 transposed weights + f32 biases (as R3).
// ---------------------------------------------------------------------------
__global__ __launch_bounds__(256)
void prep_kernel(const void* __restrict__ Wq, const void* __restrict__ bq,
                 const void* __restrict__ Wk, const void* __restrict__ bk,
                 const void* __restrict__ Wv, const void* __restrict__ bv,
                 const void* __restrict__ Wo, const void* __restrict__ bo,
                 unsigned short* __restrict__ Wt_qkv, unsigned short* __restrict__ Wt_o,
                 float* __restrict__ b_qkv, float* __restrict__ b_o,
                 const int* __restrict__ flag) {
  const int isf32 = *flag;
  const int g = (int)blockIdx.x, c = (int)threadIdx.x;
  if (g < 320) {
    float v;
    if (g < 32)      v = ld_in(Wq, (long)c * 32 + g, isf32);
    else if (g < 64) v = ld_in(Wk, (long)c * 32 + (g - 32), isf32);
    else             v = ld_in(Wv, (long)c * 256 + (g - 64), isf32);
    Wt_qkv[g * 256 + c] = f2bf(v);
  } else if (g < 576) {
    const int go = g - 320;
    Wt_o[go * 256 + c] = f2bf(ld_in(Wo, (long)c * 256 + go, isf32));
  } else if (g == 576) {
    for (int i = c; i < 320; i += 256) {
      float v = (i < 32) ? ld_in(bq, i, isf32)
              : (i < 64) ? ld_in(bk, i - 32, isf32)
                         : ld_in(bv, i - 64, isf32);
      b_qkv[i] = v;
    }
  } else {
    b_o[c] = ld_in(bo, c, isf32);
  }
}

// ---------------------------------------------------------------------------
// Kernel 2: QKV projection (as R3: streaming MFMA GEMM, LDS-transposed Vt).
// ---------------------------------------------------------------------------
__global__ __launch_bounds__(256)
void proj_kernel(const void* __restrict__ x, const unsigned short* __restrict__ Wt,
                 const float* __restrict__ b_qkv,
                 unsigned short* __restrict__ Q, unsigned short* __restrict__ Kk,
                 unsigned short* __restrict__ Vt, const int* __restrict__ flag) {
  __shared__ unsigned short Vl[64 * LDP];
  const int isf32 = *flag;
  const int t = threadIdx.x;
  const int ct = (int)(blockIdx.x % 5u);
  const long row_base = (long)(blockIdx.x / 5u) * 64;
  const int wave = t >> 6, lane = t & 63, quad = lane >> 4, l15 = lane & 15;
  const long arow = row_base + wave * 16 + l15;

  floatx4 acc[4];
  acc[0] = acc[1] = acc[2] = acc[3] = (floatx4)0.0f;

#pragma unroll
  for (int ks = 0; ks < 8; ks++) {
    short8 a;
    if (isf32) {
      const float* xf = (const float*)x + arow * 256 + ks * 32 + quad * 8;
      floatx4 f0 = *(const floatx4*)xf;
      floatx4 f1 = *(const floatx4*)(xf + 4);
#pragma unroll
      for (int j = 0; j < 4; j++) { a[j] = (short)f2bf(f0[j]); a[4 + j] = (short)f2bf(f1[j]); }
    } else {
      a = ld16((const unsigned short*)x + arow * 256 + ks * 32 + quad * 8);
    }
#pragma unroll
    for (int tn = 0; tn < 4; tn++) {
      const short8 bfr = ld16(Wt + (long)(ct * 64 + tn * 16 + l15) * 256 + ks * 32 + quad * 8);
      acc[tn] = MFMA16(a, bfr, acc[tn]);
    }
  }

  if (ct == 0) {
#pragma unroll
    for (int tn = 0; tn < 4; tn++) {
      const int g = tn * 16 + l15;
      const float bias = b_qkv[g];
#pragma unroll
      for (int r = 0; r < 4; r++) {
        const long row = row_base + wave * 16 + quad * 4 + r;
        const unsigned short h = f2bf(fmaxf(acc[tn][r] + bias, 0.0f));
        if (g < 32) Q[row * 32 + g] = h;
        else        Kk[row * 32 + (g - 32)] = h;
      }
    }
  } else {
#pragma unroll
    for (int tn = 0; tn < 4; tn++) {
      const float bias = b_qkv[ct * 64 + tn * 16 + l15];
#pragma unroll
      for (int r = 0; r < 4; r++)
        Vl[(tn * 16 + l15) * LDP + wave * 16 + quad * 4 + r] =
            f2bf(fmaxf(acc[tn][r] + bias, 0.0f));
    }
    __syncthreads();
    const int chl = t >> 2, nc = (t & 3) * 16;
    const long bb = row_base >> 12, n0 = row_base & 4095;
    unsigned short* dst = Vt + (bb * 256 + (long)(ct - 1) * 64 + chl) * 4096 + n0 + nc;
    st16(dst,     ld16(&Vl[chl * LDP + nc]));
    st16(dst + 8, ld16(&Vl[chl * LDP + nc + 8]));
  }
}

// ---------------------------------------------------------------------------
// Kernel 3: flash attention, PRODUCER/CONSUMER pipelined + fused out-proj.
// 256 blocks (batch-XCD-swizzled) x 512 threads (8 waves), 64-row Q tiles.
//   Waves 0-3 (producers): wave m owns Q-rows [16m,16m+16) x all 64 keys:
//     4 S-MFMA, exp(s-SHIFT), bf16 P store -> Pl[kt&1], running l.
//   Waves 4-7 (consumers): wave owns ALL 64 rows x 64 v-channels:
//     8 P b128 reads, 8 direct-global V frags (prefetched 1 tile), 32 MFMA.
// One barrier per tile; producer computes S(kt+1) while consumer does PV(kt).
// Each SIMD hosts 1 producer + 1 consumer -> VALU/LDS/MFMA/VMEM pipes overlap.
// ---------------------------------------------------------------------------
__global__ __launch_bounds__(512, 2)
void flash_kernel(const unsigned short* __restrict__ Q,
                  const unsigned short* __restrict__ K,
                  const unsigned short* __restrict__ Vt,
                  const unsigned short* __restrict__ Wt_o,
                  const float* __restrict__ b_o,
                  const void* __restrict__ xin, void* __restrict__ out,
                  const int* __restrict__ flag) {
  __shared__ unsigned short Pl[2][64 * LDP];   // 18.4 KB
  __shared__ unsigned short Ol[64 * LDO];      // 34.8 KB
  __shared__ float Ll[64];

  const int t = threadIdx.x;
  const int raw = (int)blockIdx.x;
  const int x8 = raw & 7;
  const int b = x8 & 3;                        // batch -> XCD pair {b, b+4}
  const int mt = (raw >> 3) | ((x8 >> 2) << 5);
  const long qrow0 = (long)b * 4096 + (long)mt * 64;
  const int wave = t >> 6, lane = t & 63, quad = lane >> 4, l15 = lane & 15;

  if (wave < 4) {
    // ---------------- producer ----------------
    const int m = wave;
    const unsigned short* kbase = K + (long)b * 4096 * 32;
    const short8 qf = ld16(Q + (qrow0 + m * 16 + l15) * 32 + quad * 8);
    short8 kb[4];
#pragma unroll
    for (int tn = 0; tn < 4; tn++)
      kb[tn] = ld16(kbase + (long)(tn * 16 + l15) * 32 + quad * 8);
    float lpart[4] = {0.0f, 0.0f, 0.0f, 0.0f};

    for (int kt = 0; kt < 64; kt++) {
      floatx4 s[4];
#pragma unroll
      for (int tn = 0; tn < 4; tn++) { s[tn] = (floatx4)0.0f; s[tn] = MFMA16(qf, kb[tn], s[tn]); }
      const int ktn = (kt + 1) & 63;
#pragma unroll
      for (int tn = 0; tn < 4; tn++)
        kb[tn] = ld16(kbase + (long)(ktn * 64 + tn * 16 + l15) * 32 + quad * 8);

      unsigned short* pl = Pl[kt & 1];
#pragma unroll
      for (int tn = 0; tn < 4; tn++)
#pragma unroll
        for (int r = 0; r < 4; r++) {
          const float p = __expf(s[tn][r] - SHIFT);
          lpart[r] += p;
          pl[(m * 16 + quad * 4 + r) * LDP + tn * 16 + l15] = f2bf(p);
        }
      __syncthreads();   // publish P(kt)
    }
    // full-row l (producer covers all 64 cols): 16-lane reduce
#pragma unroll
    for (int r = 0; r < 4; r++)
#pragma unroll
      for (int off = 1; off < 16; off <<= 1)
        lpart[r] += __shfl_xor(lpart[r], off);
    if (l15 == 0) {
      floatx4 lw;
#pragma unroll
      for (int r = 0; r < 4; r++) lw[r] = 1.0f / lpart[r];
      *(floatx4*)&Ll[m * 16 + quad * 4] = lw;
    }
    __syncthreads();   // B: Ll ready
    __syncthreads();   // B: Ol ready (written by consumers)
  } else {
    // ---------------- consumer ----------------
    const int cw = wave - 4;                    // channel group [64cw, 64cw+64)
    const unsigned short* vlane = Vt + ((long)b * 256 + cw * 64 + l15) * 4096;
    short8 vb[4][2];
#pragma unroll
    for (int tv = 0; tv < 4; tv++)
#pragma unroll
      for (int kh = 0; kh < 2; kh++)
        vb[tv][kh] = ld16(vlane + (long)tv * 16 * 4096 + kh * 32 + quad * 8);

    floatx4 oacc[4][4];
#pragma unroll
    for (int mm = 0; mm < 4; mm++)
#pragma unroll
      for (int tv = 0; tv < 4; tv++) oacc[mm][tv] = (floatx4)0.0f;

    for (int kt = 0; kt < 64; kt++) {
      __syncthreads();   // wait P(kt)
      const int ktn = (kt + 1) & 63;
      short8 vbn[4][2];
#pragma unroll
      for (int tv = 0; tv < 4; tv++)
#pragma unroll
        for (int kh = 0; kh < 2; kh++)
          vbn[tv][kh] = ld16(vlane + (long)tv * 16 * 4096 + ktn * 64 + kh * 32 + quad * 8);

      const unsigned short* plr = Pl[kt & 1];
      short8 pa[4][2];
#pragma unroll
      for (int mm = 0; mm < 4; mm++)
#pragma unroll
        for (int kh = 0; kh < 2; kh++)
          pa[mm][kh] = ld16(&plr[(mm * 16 + l15) * LDP + kh * 32 + quad * 8]);

#pragma unroll
      for (int kh = 0; kh < 2; kh++)
#pragma unroll
        for (int tv = 0; tv < 4; tv++)
#pragma unroll
          for (int mm = 0; mm < 4; mm++)
            oacc[mm][tv] = MFMA16(pa[mm][kh], vb[tv][kh], oacc[mm][tv]);

#pragma unroll
      for (int tv = 0; tv < 4; tv++)
#pragma unroll
        for (int kh = 0; kh < 2; kh++)
          vb[tv][kh] = vbn[tv][kh];
    }
    __syncthreads();   // B: Ll ready
    // normalize into Ol
#pragma unroll
    for (int mm = 0; mm < 4; mm++) {
      const floatx4 ll = *(const floatx4*)&Ll[mm * 16 + quad * 4];
#pragma unroll
      for (int tv = 0; tv < 4; tv++)
#pragma unroll
        for (int r = 0; r < 4; r++)
          Ol[(mm * 16 + quad * 4 + r) * LDO + cw * 64 + tv * 16 + l15] =
              f2bf(oacc[mm][tv][r] * ll[r]);
    }
    __syncthreads();   // B: Ol ready
  }

  // ---- fused out-projection + bias + relu + residual (all 8 waves) ----
  const int m2 = wave & 3, gh = wave >> 2;
  floatx4 acc2[8];
#pragma unroll
  for (int i = 0; i < 8; i++) acc2[i] = (floatx4)0.0f;
#pragma unroll
  for (int ks = 0; ks < 8; ks++) {
    const short8 a = ld16(&Ol[(m2 * 16 + l15) * LDO + ks * 32 + quad * 8]);
#pragma unroll
    for (int tn = 0; tn < 8; tn++) {
      const short8 bfr = ld16(Wt_o + (long)(gh * 128 + tn * 16 + l15) * 256 + ks * 32 + quad * 8);
      acc2[tn] = MFMA16(a, bfr, acc2[tn]);
    }
  }
  const int isf32 = *flag;
#pragma unroll
  for (int tn = 0; tn < 8; tn++) {
    const int g = gh * 128 + tn * 16 + l15;
    const float bias = b_o[g];
#pragma unroll
    for (int r = 0; r < 4; r++) {
      const long row = qrow0 + m2 * 16 + quad * 4 + r;
      const long gi = row * 256 + g;
      const float vv = fmaxf(acc2[tn][r] + bias, 0.0f) + ld_in(xin, gi, isf32);
      if (isf32) ((float*)out)[gi] = vv;
      else       ((unsigned short*)out)[gi] = f2bf(vv);
    }
  }
}

extern "C" void kernel_launch(void* const* d_in, const int* in_sizes, int n_in,
                              void* d_out, int out_size, void* d_ws, size_t ws_size,
                              hipStream_t stream) {
  const void* x  = d_in[0];
  const void* Wq = d_in[1]; const void* bq = d_in[2];
  const void* Wk = d_in[3]; const void* bk = d_in[4];
  const void* Wv = d_in[5]; const void* bv = d_in[6];
  const void* Wo = d_in[7]; const void* bo = d_in[8];

  char* ws = (char*)d_ws;
  int*            flag   = (int*)ws;
  unsigned short* Wt_qkv = (unsigned short*)(ws + 256);
  unsigned short* Wt_o   = (unsigned short*)(ws + 164096);
  float*          b_qkv  = (float*)(ws + 295168);
  float*          b_o    = (float*)(ws + 296448);
  unsigned short* Q      = (unsigned short*)(ws + 297472);
  unsigned short* K      = Q + (long)4 * 4096 * 32;
  unsigned short* Vt     = K + (long)4 * 4096 * 32;

  detect_kernel<<<1, 64, 0, stream>>>((const unsigned short*)x, flag);
  prep_kernel<<<578, 256, 0, stream>>>(Wq, bq, Wk, bk, Wv, bv, Wo, bo,
                                       Wt_qkv, Wt_o, b_qkv, b_o, flag);
  proj_kernel<<<1280, 256, 0, stream>>>(x, Wt_qkv, b_qkv, Q, K, Vt, flag);
  flash_kernel<<<256, 512, 0, stream>>>(Q, K, Vt, Wt_o, b_o, x, d_out, flag);
}